// Round 8
// baseline (32.223 us; speedup 1.0000x reference)
//
#include <hip/hip_runtime.h>

// Problem constants (from reference): B=32, S=256, C=50, L=20, F=30, W=3
constexpr int Bc = 32;
constexpr int Sc = 256;
constexpr int Cc = 50;
constexpr int Lc = 20;
constexpr int Fc = 30;
constexpr int Wc = 3;
constexpr int OUT_CH   = Cc * Fc;       // 1500
constexpr int CONV_LEN = Lc - Wc + 1;   // 18 -> 9 packed pairs
constexpr int NPAIR    = CONV_LEN / 2;  // 9
constexpr int XSZ      = Cc * Lc;       // 1000 floats per (b,s)
constexpr int BLOCK    = 256;
constexpr int CH_PER_T = 6;             // 6t..6t+5 never crosses a group boundary
constexpr int NP       = 4;             // positions per block
constexpr int ACT      = OUT_CH / CH_PER_T;   // 250 active lanes (== XSZ/4 stagers)

typedef float f32x2 __attribute__((ext_vector_type(2)));
typedef float f32x4 __attribute__((ext_vector_type(4)));

// Packed fp32 (CDNA2+): one VOP3P inst = 2 fp32 ops. Same rounding as fmaf.
static __device__ __forceinline__ f32x2 pk_fma(f32x2 a, f32x2 b, f32x2 c) {
    f32x2 d;
    asm("v_pk_fma_f32 %0, %1, %2, %3" : "=v"(d) : "v"(a), "v"(b), "v"(c));
    return d;
}
static __device__ __forceinline__ f32x2 pk_mul(f32x2 a, f32x2 b) {
    f32x2 d;
    asm("v_pk_mul_f32 %0, %1, %2" : "=v"(d) : "v"(a), "v"(b));
    return d;
}

// Barrier with lgkmcnt(0) only: retires this wave's own ds ops (RAW visibility
// + WAR on shared buffers); global prefetch loads stay in flight across it.
static __device__ __forceinline__ void block_sync() {
    asm volatile("s_waitcnt lgkmcnt(0)" ::: "memory");
    __builtin_amdgcn_s_barrier();
    asm volatile("" ::: "memory");
}

__global__ __launch_bounds__(BLOCK, 4)
void charcnn_kernel(const float* __restrict__ x,      // [B*S, C, L]
                    const float* __restrict__ weight, // [C*F, 1, W]
                    const float* __restrict__ bias,   // [C*F]
                    float* __restrict__ out)          // [B*S, C*F]
{
    __shared__ float xs[2][XSZ];        // double-buffered 4 KB slabs

    const int t    = threadIdx.x;
    const int pos0 = blockIdx.x * NP;
    const bool on  = (t < ACT);         // same 250 lanes stage and compute

    // ---- weights as BROADCAST PAIRS + bias, built ONCE (loop-invariant regs)
    f32x2 wp2[CH_PER_T * Wc];           // 18 pairs, both halves = w[k]
    float bb[CH_PER_T];
    if (on) {
        const float2* wp = (const float2*)(weight + t * (CH_PER_T * Wc));
        #pragma unroll
        for (int i = 0; i < (CH_PER_T * Wc) / 2; ++i) {
            const float2 q = wp[i];
            wp2[2*i + 0][0] = q.x; wp2[2*i + 0][1] = q.x;
            wp2[2*i + 1][0] = q.y; wp2[2*i + 1][1] = q.y;
        }
        const float2* bp = (const float2*)(bias + t * CH_PER_T);
        #pragma unroll
        for (int i = 0; i < CH_PER_T / 2; ++i) {
            const float2 q = bp[i];
            bb[2*i] = q.x; bb[2*i+1] = q.y;
        }
    }

    const int c = t / 5;                // group shared by this thread's 6 channels

    // ---- prologue: slab0 -> xs[0]; slab1 held in preA (ds_write at end of p=0)
    float4 preA, preB;
    if (on) {
        float4 s0 = ((const float4*)(x + (size_t)(pos0 + 0) * XSZ))[t];
        preA      = ((const float4*)(x + (size_t)(pos0 + 1) * XSZ))[t];
        ((float4*)xs[0])[t] = s0;
    }
    block_sync();

    #pragma unroll
    for (int p = 0; p < NP; ++p) {
        const int buf = p & 1;

        // Load for position p+2 issues now; its ds_write lands at end of p+1.
        if (on && (p + 2 < NP))
            preB = ((const float4*)(x + (size_t)(pos0 + p + 2) * XSZ))[t];

        if (on) {
            const float* rowf = xs[buf] + c * Lc;

            // Even pairs (v[2i], v[2i+1]): aligned -> from 5x ds_read_b128.
            f32x2 ev[Lc / 2];
            {
                const f32x4* rowv = (const f32x4*)rowf;
                #pragma unroll
                for (int i = 0; i < Lc / 4; ++i) {
                    const f32x4 q = rowv[i];
                    ev[2*i]   = __builtin_shufflevector(q, q, 0, 1);
                    ev[2*i+1] = __builtin_shufflevector(q, q, 2, 3);
                }
            }
            // Odd pairs (v[2i+1], v[2i+2]): 4-byte-aligned 8B LDS loads ->
            // compiler emits ds_read2_b32 (DS pipe, not VALU movs).
            f32x2 od[NPAIR];
            #pragma unroll
            for (int i = 0; i < NPAIR; ++i)
                od[i] = *(const f32x2*)__builtin_assume_aligned(rowf + 2*i + 1, 4);

            float res[CH_PER_T];
            #pragma unroll
            for (int j = 0; j < CH_PER_T; ++j) {
                const f32x2 w0 = wp2[3*j + 0];
                const f32x2 w1 = wp2[3*j + 1];
                const f32x2 w2 = wp2[3*j + 2];

                // cv[2i],cv[2i+1] in one 3-inst pk chain; max over the pair's
                // halves costs the SAME 9-inst max3 tree as scalar (halves are
                // plain VGPRs). Per filter: 27 pk + 9 max + 1 bias = 37 insts.
                float m;
                #pragma unroll
                for (int i = 0; i < NPAIR; ++i) {
                    const f32x2 p2 = pk_fma(ev[i], w0,
                                     pk_fma(od[i], w1,
                                     pk_mul(ev[i + 1], w2)));
                    m = (i == 0) ? fmaxf(p2[0], p2[1])
                                 : fmaxf(fmaxf(m, p2[0]), p2[1]);  // v_max3
                }
                res[j] = m + bb[j];     // bias invariant over window: hoisted past max
            }

            // Stage slab p+1 into the other buffer (compiler waits only its vmcnt).
            if (p + 1 < NP)
                ((float4*)xs[buf ^ 1])[t] = preA;

            // 6 floats at out + (pos0+p)*1500 + 6t: contiguous across lanes.
            float* op = out + (size_t)(pos0 + p) * OUT_CH + t * CH_PER_T;
            #pragma unroll
            for (int i = 0; i < CH_PER_T / 2; ++i)
                ((float2*)op)[i] = make_float2(res[2*i], res[2*i+1]);

            preA = preB;                // slab p+2 becomes next to stage
        }

        if (p + 1 < NP) block_sync();   // lgkmcnt-only: prefetch survives barrier
    }
}

extern "C" void kernel_launch(void* const* d_in, const int* in_sizes, int n_in,
                              void* d_out, int out_size, void* d_ws, size_t ws_size,
                              hipStream_t stream) {
    const float* x      = (const float*)d_in[0];  // [B,S,C,L] fp32
    const float* weight = (const float*)d_in[1];  // [C*F,1,W] fp32
    const float* bias   = (const float*)d_in[2];  // [C*F] fp32
    float* out          = (float*)d_out;          // [B,S,C*F] fp32

    const int nBlocks = (Bc * Sc) / NP;           // 2048 blocks (8 blocks/CU)
    charcnn_kernel<<<nBlocks, BLOCK, 0, stream>>>(x, weight, bias, out);
}

// Round 9
// 27.530 us; speedup vs baseline: 1.1705x; 1.1705x over previous
//
#include <hip/hip_runtime.h>

// Problem constants (from reference): B=32, S=256, C=50, L=20, F=30, W=3
constexpr int Bc = 32;
constexpr int Sc = 256;
constexpr int Cc = 50;
constexpr int Lc = 20;
constexpr int Fc = 30;
constexpr int Wc = 3;
constexpr int OUT_CH   = Cc * Fc;       // 1500
constexpr int CONV_LEN = Lc - Wc + 1;   // 18
constexpr int XSZ      = Cc * Lc;       // 1000 floats per (b,s)
constexpr int BLOCK    = 512;           // 8 waves/block
constexpr int CH_PER_T = 3;             // 3t..3t+2 never crosses a group boundary
constexpr int NP       = 8;             // positions per block -> 1024 blocks, 1 round
constexpr int ACT      = OUT_CH / CH_PER_T;   // 500 active compute lanes
constexpr int STG      = XSZ / 4;             // 250 stager lanes (float4 each)

// Barrier with lgkmcnt(0) only: retires this wave's own ds ops (RAW visibility
// + WAR on shared buffers); global prefetch loads stay in flight across it.
static __device__ __forceinline__ void block_sync() {
    asm volatile("s_waitcnt lgkmcnt(0)" ::: "memory");
    __builtin_amdgcn_s_barrier();
    asm volatile("" ::: "memory");
}

// __launch_bounds__(512, 8): 8 waves/EU minimum -> compiler MUST fit 64 VGPRs.
// 4 blocks/CU x 8 waves = 32 waves/CU (max occupancy); LDS 8KB -> not limiting.
__global__ __launch_bounds__(BLOCK, 8)
void charcnn_kernel(const float* __restrict__ x,      // [B*S, C, L]
                    const float* __restrict__ weight, // [C*F, 1, W]
                    const float* __restrict__ bias,   // [C*F]
                    float* __restrict__ out)          // [B*S, C*F]
{
    __shared__ float xs[2][XSZ];        // double-buffered 4 KB slabs

    const int t    = threadIdx.x;
    const int pos0 = blockIdx.x * NP;
    const bool on  = (t < ACT);         // 500 compute lanes
    const bool stg = (t < STG);         // 250 staging lanes

    // ---- weights/bias once per thread: 9 + 3 scalars (register-lean)
    float w[CH_PER_T * Wc];             // 9 floats at weight + 9t (scalar loads)
    float bb[CH_PER_T];
    if (on) {
        const float* wp = weight + t * (CH_PER_T * Wc);
        #pragma unroll
        for (int i = 0; i < CH_PER_T * Wc; ++i) w[i] = wp[i];
        const float* bp = bias + t * CH_PER_T;
        #pragma unroll
        for (int i = 0; i < CH_PER_T; ++i) bb[i] = bp[i];
    }

    const int c = t / 10;               // group shared by this thread's 3 channels

    // ---- prologue: stage slab0 into xs[0]
    if (stg)
        ((float4*)xs[0])[t] = ((const float4*)(x + (size_t)pos0 * XSZ))[t];
    block_sync();

    #pragma unroll 2                    // static buf indices, modest code size
    for (int p = 0; p < NP; ++p) {
        const int buf = p & 1;

        // Issue next slab's load FIRST: latency hides under this position's compute.
        float4 preA;
        if (stg && (p + 1 < NP))
            preA = ((const float4*)(x + (size_t)(pos0 + p + 1) * XSZ))[t];

        if (on) {
            // Row: 80 B, 16B-aligned -> 5x ds_read_b128 (10 lanes share a row).
            float v[Lc];
            {
                const float4* rowv = (const float4*)(xs[buf] + c * Lc);
                #pragma unroll
                for (int i = 0; i < Lc / 4; ++i) {
                    const float4 q = rowv[i];
                    v[4*i+0] = q.x; v[4*i+1] = q.y; v[4*i+2] = q.z; v[4*i+3] = q.w;
                }
            }

            float* op = out + (size_t)(pos0 + p) * OUT_CH + t * CH_PER_T;
            #pragma unroll
            for (int j = 0; j < CH_PER_T; ++j) {
                const float w0 = w[3*j + 0];
                const float w1 = w[3*j + 1];
                const float w2 = w[3*j + 2];

                // Running max, two windows per step -> v_max3 fusion; no cv array.
                float m = fmaf(v[0], w0, fmaf(v[1], w1, v[2] * w2));
                #pragma unroll
                for (int q = 1; q + 1 < CONV_LEN; q += 2) {
                    const float a = fmaf(v[q],   w0, fmaf(v[q+1], w1, v[q+2] * w2));
                    const float b = fmaf(v[q+1], w0, fmaf(v[q+2], w1, v[q+3] * w2));
                    m = fmaxf(fmaxf(m, a), b);
                }
                m = fmaxf(m, fmaf(v[CONV_LEN-1], w0,
                           fmaf(v[CONV_LEN],     w1, v[CONV_LEN+1] * w2)));

                op[j] = m + bb[j];      // bias hoisted past max (window-invariant)
            }
        }

        // Stage slab p+1 into the other buffer; barrier separates it from readers.
        if (stg && (p + 1 < NP))
            ((float4*)xs[buf ^ 1])[t] = preA;

        if (p + 1 < NP) block_sync();   // lgkmcnt-only: prefetch survives barrier
    }
}

extern "C" void kernel_launch(void* const* d_in, const int* in_sizes, int n_in,
                              void* d_out, int out_size, void* d_ws, size_t ws_size,
                              hipStream_t stream) {
    const float* x      = (const float*)d_in[0];  // [B,S,C,L] fp32
    const float* weight = (const float*)d_in[1];  // [C*F,1,W] fp32
    const float* bias   = (const float*)d_in[2];  // [C*F] fp32
    float* out          = (float*)d_out;          // [B,S,C*F] fp32

    const int nBlocks = (Bc * Sc) / NP;           // 1024 blocks = 1 residency round
    charcnn_kernel<<<nBlocks, BLOCK, 0, stream>>>(x, weight, bias, out);
}